// Round 13
// baseline (1196.835 us; speedup 1.0000x reference)
//
#include <hip/hip_runtime.h>
#include <math.h>

// Problem constants
#define BB 2
#define TT 2048
#define CC 768
#define HH 12
#define NN 64
#define GG 2
#define CG 384   // C/G
#define FF 3145728L   // B*C*T
#define S1 1572864L   // B*384*T

typedef __attribute__((ext_vector_type(8))) short bf8frag;   // 8 bf16 (4 VGPRs)
typedef __attribute__((ext_vector_type(4))) float f4acc;     // 4 fp32 acc

__device__ inline unsigned short f2bf(float x) {
    union { float f; unsigned u; } v; v.f = x;
    unsigned r = v.u + 0x7FFFu + ((v.u >> 16) & 1u);   // RNE
    return (unsigned short)(r >> 16);
}
__device__ inline float bf2f(unsigned short u) {
    union { unsigned u; float f; } v; v.u = ((unsigned)u) << 16;
    return v.f;
}

// ---------------------------------------------------------------------------
// Generic fp32 tiled GEMM v1: 64x64 tile, 256 threads, 4x4 micro-tile.
// bfout: optional bf16 side-write (mix GEMM emits bf16 xr/xk/xv copies).
// MODE==2: fp32 store skipped for zi in {0,3} (xr/xv fp32 never read).
// ---------------------------------------------------------------------------
template<int ATRANS, int BTRANS, int TOUT, int MODE>
__global__ __launch_bounds__(256) void gemm_kernel(
    const float* __restrict__ A, const float* __restrict__ Bm, float* __restrict__ Cm,
    const float* __restrict__ aux, const float* __restrict__ aux2,
    int K, int ldA, int ldB, int ldC, int zInner,
    long sA_o, long sA_i, long sB_o, long sB_i, long sC_o, long sC_i,
    long sAux_i, long sAux2_o, unsigned short* bfout)
{
    const int zo = blockIdx.z / zInner;
    const int zi = blockIdx.z % zInner;
    A  += (size_t)zo * sA_o + (size_t)zi * sA_i;
    Bm += (size_t)zo * sB_o + (size_t)zi * sB_i;
    Cm += (size_t)zo * sC_o + (size_t)zi * sC_i;
    if (MODE == 2) { aux += (size_t)zi * sAux_i; aux2 += (size_t)zo * sAux2_o; }

    const int m0t = blockIdx.y * 64;
    const int n0t = blockIdx.x * 64;
    const int tid = threadIdx.x;

    __shared__ float As[16][64];
    __shared__ float Bs[16][64];

    int mi, ni;
    if (TOUT) { mi = (tid & 15) * 4; ni = (tid >> 4) * 4; }
    else      { ni = (tid & 15) * 4; mi = (tid >> 4) * 4; }

    float acc[4][4];
#pragma unroll
    for (int i = 0; i < 4; ++i)
#pragma unroll
        for (int j = 0; j < 4; ++j) acc[i][j] = 0.f;

    for (int k0 = 0; k0 < K; k0 += 16) {
        if (!ATRANS) {
            const int row = tid >> 2;
            const int kc  = (tid & 3) * 4;
            float4 av = *(const float4*)&A[(size_t)(m0t + row) * ldA + k0 + kc];
            As[kc + 0][row] = av.x; As[kc + 1][row] = av.y;
            As[kc + 2][row] = av.z; As[kc + 3][row] = av.w;
        } else {
            const int krow = tid >> 4;
            const int mc   = (tid & 15) * 4;
            *(float4*)&As[krow][mc] = *(const float4*)&A[(size_t)(k0 + krow) * ldA + m0t + mc];
        }
        if (!BTRANS) {
            const int krow = tid >> 4;
            const int tc   = (tid & 15) * 4;
            *(float4*)&Bs[krow][tc] = *(const float4*)&Bm[(size_t)(k0 + krow) * ldB + n0t + tc];
        } else {
            const int trow = tid >> 2;
            const int kc   = (tid & 3) * 4;
            float4 bv = *(const float4*)&Bm[(size_t)(n0t + trow) * ldB + k0 + kc];
            Bs[kc + 0][trow] = bv.x; Bs[kc + 1][trow] = bv.y;
            Bs[kc + 2][trow] = bv.z; Bs[kc + 3][trow] = bv.w;
        }
        __syncthreads();
#pragma unroll
        for (int kk = 0; kk < 16; ++kk) {
            float4 a4 = *(const float4*)&As[kk][mi];
            float4 b4 = *(const float4*)&Bs[kk][ni];
            float am[4] = {a4.x, a4.y, a4.z, a4.w};
            float bn[4] = {b4.x, b4.y, b4.z, b4.w};
#pragma unroll
            for (int i = 0; i < 4; ++i)
#pragma unroll
                for (int j = 0; j < 4; ++j) acc[i][j] = fmaf(am[i], bn[j], acc[i][j]);
        }
        __syncthreads();
    }

    const int mbase = m0t + mi, nbase = n0t + ni;
#pragma unroll
    for (int i = 0; i < 4; ++i) {
        float4 xv;
        if (MODE == 2) xv = *(const float4*)&aux2[(size_t)(mbase + i) * ldC + nbase];
        float xa[4] = {0.f, 0.f, 0.f, 0.f};
        if (MODE == 2) { xa[0] = xv.x; xa[1] = xv.y; xa[2] = xv.z; xa[3] = xv.w; }
#pragma unroll
        for (int j = 0; j < 4; ++j) {
            float v = acc[i][j];
            if (MODE == 1) v = tanhf(v);
            else if (MODE == 2) v = xa[j] * (aux[mbase + i] + v);
            else if (MODE == 3) {
                float u  = aux[mbase + i] + v;
                float sp = fmaxf(-u, 0.f) + log1pf(expf(-fabsf(u)));  // softplus(-u)
                float wl = -sp - 0.5f;
                v = expf(-expf(wl));
            } else if (MODE == 4) {
                float u = aux[mbase + i] + v;
                v = 1.f / (1.f + expf(-u));
            }
            acc[i][j] = v;
        }
    }
    if (!TOUT) {
        const bool skipf = (MODE == 2) && (bfout != nullptr) && (zi == 0 || zi == 3);
        if (!skipf) {
#pragma unroll
            for (int i = 0; i < 4; ++i) {
                float4 o = {acc[i][0], acc[i][1], acc[i][2], acc[i][3]};
                *(float4*)&Cm[(size_t)(mbase + i) * ldC + nbase] = o;
            }
        }
        // bf16 side-write for MFMA conv inputs: slots n in {0:xr, 2:xk, 3:xv}
        if (MODE == 2 && bfout != nullptr) {
            int sidx = (zi == 0) ? 0 : (zi == 2) ? 1 : (zi == 3) ? 2 : -1;
            if (sidx >= 0) {
                unsigned short* bp = bfout + (size_t)sidx * FF + (size_t)zo * ((long)CC * TT);
#pragma unroll
                for (int i = 0; i < 4; ++i) {
                    ushort4 o = {f2bf(acc[i][0]), f2bf(acc[i][1]), f2bf(acc[i][2]), f2bf(acc[i][3])};
                    *(ushort4*)&bp[(size_t)(mbase + i) * ldC + nbase] = o;
                }
            }
        }
    } else {
#pragma unroll
        for (int j = 0; j < 4; ++j) {
            float4 o = {acc[0][j], acc[1][j], acc[2][j], acc[3][j]};
            *(float4*)&Cm[(size_t)(nbase + j) * ldC + mbase] = o;
        }
    }
}

// ---------------------------------------------------------------------------
// Merged lora-hidden GEMMs (decay/aaa/kkk/gate _w1): tanh(W @ x_slot).
// grid (32,3,8): z = which*2 + b; which<3 uses only blockIdx.y==0 (M=64).
// ---------------------------------------------------------------------------
__global__ __launch_bounds__(256) void lorah_kernel(
    const float* __restrict__ w0, const float* __restrict__ w1,
    const float* __restrict__ w2, const float* __restrict__ w3,
    const float* __restrict__ x0, const float* __restrict__ x1,
    const float* __restrict__ x2, const float* __restrict__ x3,
    float* __restrict__ o0, float* __restrict__ o1,
    float* __restrict__ o2, float* __restrict__ o3)
{
    const int z = blockIdx.z;
    const int which = z >> 1, bz = z & 1;
    if (which < 3 && blockIdx.y > 0) return;
    const float* A; const float* Bm; float* Cm; int M;
    if (which == 0)      { A = w0; Bm = x0; Cm = o0; M = 64; }
    else if (which == 1) { A = w1; Bm = x1; Cm = o1; M = 64; }
    else if (which == 2) { A = w2; Bm = x2; Cm = o2; M = 64; }
    else                 { A = w3; Bm = x3; Cm = o3; M = 192; }
    Bm += (size_t)bz * ((long)CC * TT);
    Cm += (size_t)bz * ((long)M * TT);

    const int m0t = blockIdx.y * 64;
    const int n0t = blockIdx.x * 64;
    const int tid = threadIdx.x;

    __shared__ float As[16][64];
    __shared__ float Bs[16][64];

    const int ni = (tid & 15) * 4, mi = (tid >> 4) * 4;
    float acc[4][4];
#pragma unroll
    for (int i = 0; i < 4; ++i)
#pragma unroll
        for (int j = 0; j < 4; ++j) acc[i][j] = 0.f;

    for (int k0 = 0; k0 < CC; k0 += 16) {
        {
            const int row = tid >> 2, kc = (tid & 3) * 4;
            float4 av = *(const float4*)&A[(size_t)(m0t + row) * CC + k0 + kc];
            As[kc + 0][row] = av.x; As[kc + 1][row] = av.y;
            As[kc + 2][row] = av.z; As[kc + 3][row] = av.w;
        }
        {
            const int krow = tid >> 4, tc = (tid & 15) * 4;
            *(float4*)&Bs[krow][tc] = *(const float4*)&Bm[(size_t)(k0 + krow) * TT + n0t + tc];
        }
        __syncthreads();
#pragma unroll
        for (int kk = 0; kk < 16; ++kk) {
            float4 a4 = *(const float4*)&As[kk][mi];
            float4 b4 = *(const float4*)&Bs[kk][ni];
            float am[4] = {a4.x, a4.y, a4.z, a4.w};
            float bn[4] = {b4.x, b4.y, b4.z, b4.w};
#pragma unroll
            for (int i = 0; i < 4; ++i)
#pragma unroll
                for (int j = 0; j < 4; ++j) acc[i][j] = fmaf(am[i], bn[j], acc[i][j]);
        }
        __syncthreads();
    }
    const int mbase = m0t + mi, nbase = n0t + ni;
#pragma unroll
    for (int i = 0; i < 4; ++i) {
        float4 o = {tanhf(acc[i][0]), tanhf(acc[i][1]), tanhf(acc[i][2]), tanhf(acc[i][3])};
        *(float4*)&Cm[(size_t)(mbase + i) * TT + nbase] = o;
    }
}

// ---------------------------------------------------------------------------
// Merged 3 input convs via bf16 MFMA: grid (16,3,12), z = conv*4 + b*2 + g.
// Per (b,g): C(384x2048) = W(384x384) X(384x2048), X as (B,T,C) bf16.
// Out: fp32 (B,T,C) into X6 slot {1,4,5} per conv.
// ---------------------------------------------------------------------------
__global__ __launch_bounds__(256) void convs3_mfma_kernel(
    const unsigned short* __restrict__ wball, const unsigned short* __restrict__ X6t,
    float* __restrict__ X6)
{
    const int z = blockIdx.z;
    const int conv = z >> 2, bg = z & 3, b = bg >> 1, g = bg & 1;
    const unsigned short* Wb = wball + (size_t)conv * 294912;
    const unsigned short* Xb = X6t + (size_t)conv * FF;
    const int oslot = (conv == 0) ? 1 : (conv == 1) ? 4 : 5;
    float* Cout = X6 + (size_t)oslot * FF;

    const int t0 = blockIdx.x * 128;
    const int m0 = blockIdx.y * 128;
    const int tid = threadIdx.x;
    const int wave = tid >> 6, lane = tid & 63;
    const int lq = lane >> 4, lr = lane & 15;

    __shared__ unsigned short Ws[128 * 40];
    __shared__ unsigned short Xs[128 * 40];

    const unsigned short* Wg = Wb + (size_t)g * (CG * CG);
    const long xbase = (long)b * (long)TT * CC;

    f4acc acc0[8], acc1[8];
#pragma unroll
    for (int j = 0; j < 8; ++j) { acc0[j] = (f4acc)0.f; acc1[j] = (f4acc)0.f; }

    for (int k0 = 0; k0 < CG; k0 += 32) {
        {
            const int m = tid >> 1, kc = (tid & 1) * 16;
            const unsigned short* src = Wg + (size_t)(m0 + m) * CG + k0 + kc;
            *(bf8frag*)&Ws[m * 40 + kc]     = *(const bf8frag*)src;
            *(bf8frag*)&Ws[m * 40 + kc + 8] = *(const bf8frag*)(src + 8);
        }
        {
            const int t = tid >> 1, kc = (tid & 1) * 16;
            const unsigned short* src = Xb + xbase + (long)(t0 + t) * CC + g * CG + k0 + kc;
            *(bf8frag*)&Xs[t * 40 + kc]     = *(const bf8frag*)src;
            *(bf8frag*)&Xs[t * 40 + kc + 8] = *(const bf8frag*)(src + 8);
        }
        __syncthreads();

        bf8frag a0 = *(const bf8frag*)&Ws[(32 * wave + lr) * 40 + lq * 8];
        bf8frag a1 = *(const bf8frag*)&Ws[(32 * wave + 16 + lr) * 40 + lq * 8];
#pragma unroll
        for (int nj = 0; nj < 8; ++nj) {
            bf8frag bb = *(const bf8frag*)&Xs[(16 * nj + lr) * 40 + lq * 8];
            acc0[nj] = __builtin_amdgcn_mfma_f32_16x16x32_bf16(a0, bb, acc0[nj], 0, 0, 0);
            acc1[nj] = __builtin_amdgcn_mfma_f32_16x16x32_bf16(a1, bb, acc1[nj], 0, 0, 0);
        }
        __syncthreads();
    }

#pragma unroll
    for (int fi = 0; fi < 2; ++fi) {
        const int cbase = m0 + 32 * wave + 16 * fi + lq * 4;
#pragma unroll
        for (int nj = 0; nj < 8; ++nj) {
            const f4acc av = fi ? acc1[nj] : acc0[nj];
            const int t = t0 + 16 * nj + lr;
            float4 o = {av[0], av[1], av[2], av[3]};
            *(float4*)&Cout[(long)b * (long)TT * CC + (long)t * CC + g * CG + cbase] = o;
        }
    }
}

// ---------------------------------------------------------------------------
// Output conv via bf16 MFMA: z (B,T,C) bf16 -> out (B,C,T) fp32.
// ---------------------------------------------------------------------------
__global__ __launch_bounds__(256) void convout_mfma_kernel(
    const unsigned short* __restrict__ Wb, const unsigned short* __restrict__ Xb,
    float* __restrict__ Cout)
{
    const int bz = blockIdx.z; const int b = bz >> 1, g = bz & 1;
    const int t0 = blockIdx.x * 128;
    const int m0 = blockIdx.y * 128;
    const int tid = threadIdx.x;
    const int wave = tid >> 6, lane = tid & 63;
    const int lq = lane >> 4, lr = lane & 15;

    __shared__ unsigned short Ws[128 * 40];
    __shared__ unsigned short Xs[128 * 40];

    const unsigned short* Wg = Wb + (size_t)g * (CG * CG);
    const long xbase = (long)b * (long)TT * CC;

    f4acc acc0[8], acc1[8];
#pragma unroll
    for (int j = 0; j < 8; ++j) { acc0[j] = (f4acc)0.f; acc1[j] = (f4acc)0.f; }

    for (int k0 = 0; k0 < CG; k0 += 32) {
        {
            const int m = tid >> 1, kc = (tid & 1) * 16;
            const unsigned short* src = Wg + (size_t)(m0 + m) * CG + k0 + kc;
            *(bf8frag*)&Ws[m * 40 + kc]     = *(const bf8frag*)src;
            *(bf8frag*)&Ws[m * 40 + kc + 8] = *(const bf8frag*)(src + 8);
        }
        {
            const int t = tid >> 1, kc = (tid & 1) * 16;
            const unsigned short* src = Xb + xbase + (long)(t0 + t) * CC + g * CG + k0 + kc;
            *(bf8frag*)&Xs[t * 40 + kc]     = *(const bf8frag*)src;
            *(bf8frag*)&Xs[t * 40 + kc + 8] = *(const bf8frag*)(src + 8);
        }
        __syncthreads();

        bf8frag a0 = *(const bf8frag*)&Ws[(32 * wave + lr) * 40 + lq * 8];
        bf8frag a1 = *(const bf8frag*)&Ws[(32 * wave + 16 + lr) * 40 + lq * 8];
#pragma unroll
        for (int nj = 0; nj < 8; ++nj) {
            bf8frag bb = *(const bf8frag*)&Xs[(16 * nj + lr) * 40 + lq * 8];
            acc0[nj] = __builtin_amdgcn_mfma_f32_16x16x32_bf16(a0, bb, acc0[nj], 0, 0, 0);
            acc1[nj] = __builtin_amdgcn_mfma_f32_16x16x32_bf16(a1, bb, acc1[nj], 0, 0, 0);
        }
        __syncthreads();
    }

#pragma unroll
    for (int fi = 0; fi < 2; ++fi) {
        const int cbase = m0 + 32 * wave + 16 * fi + lq * 4;
#pragma unroll
        for (int nj = 0; nj < 8; ++nj) {
            const f4acc av = fi ? acc1[nj] : acc0[nj];
            const int t = t0 + 16 * nj + lr;
#pragma unroll
            for (int i = 0; i < 4; ++i)
                Cout[(long)b * (long)CC * TT + (long)(g * CG + cbase + i) * TT + t] = av[i];
        }
    }
}

// ---------------------------------------------------------------------------
// maa_w1 bf16 MFMA GEMM: tm(b,384,T) = tanh( W(384x768) @ x(b,768,T) ).
// ---------------------------------------------------------------------------
__global__ __launch_bounds__(256) void maaw1_mfma_kernel(
    const unsigned short* __restrict__ Wb, const unsigned short* __restrict__ Xb,
    float* __restrict__ Cout)
{
    const int b = blockIdx.z;
    const int t0 = blockIdx.x * 128;
    const int m0 = blockIdx.y * 128;
    const int tid = threadIdx.x;
    const int wave = tid >> 6, lane = tid & 63;
    const int lq = lane >> 4, lr = lane & 15;

    __shared__ unsigned short Ws[128 * 40];
    __shared__ unsigned short Xs[128 * 40];

    const long xbase = (long)b * (long)TT * CC;

    f4acc acc0[8], acc1[8];
#pragma unroll
    for (int j = 0; j < 8; ++j) { acc0[j] = (f4acc)0.f; acc1[j] = (f4acc)0.f; }

    for (int k0 = 0; k0 < CC; k0 += 32) {
        {
            const int m = tid >> 1, kc = (tid & 1) * 16;
            const unsigned short* src = Wb + (size_t)(m0 + m) * CC + k0 + kc;
            *(bf8frag*)&Ws[m * 40 + kc]     = *(const bf8frag*)src;
            *(bf8frag*)&Ws[m * 40 + kc + 8] = *(const bf8frag*)(src + 8);
        }
        {
            const int t = tid >> 1, kc = (tid & 1) * 16;
            const unsigned short* src = Xb + xbase + (long)(t0 + t) * CC + k0 + kc;
            *(bf8frag*)&Xs[t * 40 + kc]     = *(const bf8frag*)src;
            *(bf8frag*)&Xs[t * 40 + kc + 8] = *(const bf8frag*)(src + 8);
        }
        __syncthreads();

        bf8frag a0 = *(const bf8frag*)&Ws[(32 * wave + lr) * 40 + lq * 8];
        bf8frag a1 = *(const bf8frag*)&Ws[(32 * wave + 16 + lr) * 40 + lq * 8];
#pragma unroll
        for (int nj = 0; nj < 8; ++nj) {
            bf8frag bb = *(const bf8frag*)&Xs[(16 * nj + lr) * 40 + lq * 8];
            acc0[nj] = __builtin_amdgcn_mfma_f32_16x16x32_bf16(a0, bb, acc0[nj], 0, 0, 0);
            acc1[nj] = __builtin_amdgcn_mfma_f32_16x16x32_bf16(a1, bb, acc1[nj], 0, 0, 0);
        }
        __syncthreads();
    }

#pragma unroll
    for (int fi = 0; fi < 2; ++fi) {
        const int m = m0 + 32 * wave + 16 * fi + lq * 4;
#pragma unroll
        for (int nj = 0; nj < 8; ++nj) {
            const f4acc av = fi ? acc1[nj] : acc0[nj];
            const int t = t0 + 16 * nj + lr;
#pragma unroll
            for (int i = 0; i < 4; ++i)
                Cout[(long)b * 384 * TT + (long)(m + i) * TT + t] = tanhf(av[i]);
        }
    }
}

// ---------------------------------------------------------------------------
// Transpose kernels (LDS 64x64 tiles)
// ---------------------------------------------------------------------------
__global__ __launch_bounds__(256) void xtr_kernel(const float* __restrict__ xin,
                                                  unsigned short* __restrict__ xout)
{
    __shared__ unsigned short L[64][68];
    const int t0 = blockIdx.x * 64, c0 = blockIdx.y * 64, b = blockIdx.z;
    const int tid = threadIdx.x;
    const int lr = tid >> 4, lc = (tid & 15) * 4;
#pragma unroll
    for (int i = 0; i < 4; ++i) {
        int c = lr + i * 16;
        float4 v = *(const float4*)&xin[(size_t)b * CC * TT + (size_t)(c0 + c) * TT + t0 + lc];
        L[c][lc + 0] = f2bf(v.x); L[c][lc + 1] = f2bf(v.y);
        L[c][lc + 2] = f2bf(v.z); L[c][lc + 3] = f2bf(v.w);
    }
    __syncthreads();
#pragma unroll
    for (int i = 0; i < 4; ++i) {
        int t = lr + i * 16;
        ushort4 o = {L[lc + 0][t], L[lc + 1][t], L[lc + 2][t], L[lc + 3][t]};
        *(ushort4*)&xout[(size_t)b * TT * CC + (size_t)(t0 + t) * CC + c0 + lc] = o;
    }
}

__global__ __launch_bounds__(256) void btr_kernel(const unsigned short* __restrict__ xin,
                                                  unsigned short* __restrict__ xout)
{
    __shared__ unsigned short L[64][68];
    const int t0 = blockIdx.x * 64, c0 = blockIdx.y * 64;
    const int s = blockIdx.z >> 1, b = blockIdx.z & 1;
    const int tid = threadIdx.x;
    const int lr = tid >> 4, lc = (tid & 15) * 4;
    const size_t ibase = (size_t)s * FF + (size_t)b * CC * TT;
    const size_t obase = (size_t)s * FF + (size_t)b * TT * CC;
#pragma unroll
    for (int i = 0; i < 4; ++i) {
        int c = lr + i * 16;
        ushort4 v = *(const ushort4*)&xin[ibase + (size_t)(c0 + c) * TT + t0 + lc];
        L[c][lc + 0] = v.x; L[c][lc + 1] = v.y; L[c][lc + 2] = v.z; L[c][lc + 3] = v.w;
    }
    __syncthreads();
#pragma unroll
    for (int i = 0; i < 4; ++i) {
        int t = lr + i * 16;
        ushort4 o = {L[lc + 0][t], L[lc + 1][t], L[lc + 2][t], L[lc + 3][t]};
        *(ushort4*)&xout[obase + (size_t)(t0 + t) * CC + c0 + lc] = o;
    }
}

// ---------------------------------------------------------------------------
__global__ void wcvt_kernel(const float* __restrict__ w0, const float* __restrict__ w1,
                            const float* __restrict__ w2, const float* __restrict__ w3,
                            const float* __restrict__ w4, unsigned short* __restrict__ wb)
{
    const int i = blockIdx.x * 256 + threadIdx.x;   // total 5*294912
    const int which = i / 294912, r = i - which * 294912;
    const float* s = (which == 0) ? w0 : (which == 1) ? w1 : (which == 2) ? w2
                   : (which == 3) ? w3 : w4;
    wb[i] = f2bf(s[r]);
}

// ---------------------------------------------------------------------------
__global__ void pack_aux_kernel(const float* __restrict__ r, const float* __restrict__ w,
                                const float* __restrict__ k, const float* __restrict__ v,
                                const float* __restrict__ a, const float* __restrict__ g,
                                float* __restrict__ paux)
{
    int c = blockIdx.x * blockDim.x + threadIdx.x;
    if (c < CC) {
        paux[0 * CC + c] = 1.f + r[c];
        paux[1 * CC + c] = 1.f + w[c];
        paux[2 * CC + c] = 1.f + k[c];
        paux[3 * CC + c] = 1.f + v[c];
        paux[4 * CC + c] = 1.f + a[c];
        paux[5 * CC + c] = 1.f + g[c];
    }
}

// ---------------------------------------------------------------------------
// E1: per token, kk = k + kvec; per-head L2-normalize; aa=-kkn, b2=kkn*a.
// ---------------------------------------------------------------------------
__global__ __launch_bounds__(256) void e1_kernel(const float* __restrict__ kA,
                                                 float* __restrict__ kvecA,
                                                 float* __restrict__ aA)
{
    const size_t base = (size_t)blockIdx.x * CC;
    const int tid = threadIdx.x;
#pragma unroll
    for (int ch = 0; ch < 3; ++ch) {
        int c = ch * 256 + tid;
        float kk = kA[base + c] + kvecA[base + c];
        float ss = kk * kk;
#pragma unroll
        for (int off = 32; off; off >>= 1) ss += __shfl_xor(ss, off, 64);
        float denom = fmaxf(sqrtf(ss), 1e-12f);
        float kkn = kk / denom;
        float av = aA[base + c];
        kvecA[base + c] = -kkn;       // aa
        aA[base + c]    = kkn * av;   // b2
    }
}

// ---------------------------------------------------------------------------
// WKV-7 v10 + fused gate_w2:
//  Blocks 0..47: wkv. 4 waves/block, wave = rg-quad: bh = blk%24,
//    rg = (blk/24)*4 + wave. Same per-wave math as v9 (8-way column split,
//    SADDR addressing, 3-deep prefetch) EXCEPT the y cross-lane reduction is
//    DELETED: every lane stores its bf16 partial into yp8[jg] — zero
//    cross-lane dependency at step end. e2 sums the 8 planes.
//    24%8==0 keeps all 8 rg of a (b,h) on one XCD; 4 now share one CU's L1.
//  Blocks 48..815: gate_w2 GEMM (gbuf = (gate_w2 @ gh)^T), running on the
//    CUs wkv leaves idle — free.
// ---------------------------------------------------------------------------
struct WFrag {
    float4 w[2], a[2], b[2], k[2], r[2];
    float vv;
};

__global__ __launch_bounds__(256) void wkvgate_kernel(
    const float* __restrict__ rA, const float* __restrict__ wA,
    const float* __restrict__ kA, const float* __restrict__ vA,
    const float* __restrict__ aaA, const float* __restrict__ b2A,
    unsigned short* __restrict__ yp8,
    const float* __restrict__ gw2, const float* __restrict__ gh,
    float* __restrict__ gbuf)
{
    __shared__ float As[16][64];
    __shared__ float Bs[16][64];
    const int blk = blockIdx.x;
    const int tid = threadIdx.x;

    if (blk < 48) {
        const int wave = tid >> 6, lane = tid & 63;
        const int bh = blk % 24, rg = (blk / 24) * 4 + wave;
        const int b = bh / HH, h = bh - b * HH;
        const int jg = lane >> 3, p = lane & 7;
        const int row = rg * 8 + p;
        const int base = b * TT * CC + h * NN;
        const int fo = jg * 8;
        const int ybase = (jg * BB + b) * (TT * CC) + h * NN + row;

        float S[8];
#pragma unroll
        for (int i = 0; i < 8; ++i) S[i] = 0.f;

        WFrag f0, f1, f2;

        auto loadfrag = [&](WFrag& f, int t) {
            const int o = base + t * CC + fo;
#pragma unroll
            for (int q = 0; q < 2; ++q) {
                f.w[q] = *(const float4*)&wA[o + 4 * q];
                f.a[q] = *(const float4*)&aaA[o + 4 * q];
                f.b[q] = *(const float4*)&b2A[o + 4 * q];
                f.k[q] = *(const float4*)&kA[o + 4 * q];
                f.r[q] = *(const float4*)&rA[o + 4 * q];
            }
            f.vv = vA[base + t * CC + row];
        };

        auto stepf = [&](const WFrag& f, int t) {
            const float vv = f.vv;
            float vk[8];
#pragma unroll
            for (int q = 0; q < 2; ++q) {
                vk[4*q+0] = vv * f.k[q].x;
                vk[4*q+1] = vv * f.k[q].y;
                vk[4*q+2] = vv * f.k[q].z;
                vk[4*q+3] = vv * f.k[q].w;
            }

            float t0 = 0.f, t1 = 0.f, t2 = 0.f, t3 = 0.f;
#pragma unroll
            for (int q = 0; q < 2; ++q) {
                float4 a4 = f.a[q];
                t0 = fmaf(S[4*q+0], a4.x, t0);
                t1 = fmaf(S[4*q+1], a4.y, t1);
                t2 = fmaf(S[4*q+2], a4.z, t2);
                t3 = fmaf(S[4*q+3], a4.w, t3);
            }
            float part = (t0 + t1) + (t2 + t3);
            float s08 = __shfl_xor(part,  8, 64);
            float s16 = __shfl_xor(part, 16, 64);
            float s24 = __shfl_xor(part, 24, 64);
            float s32 = __shfl_xor(part, 32, 64);
            float s40 = __shfl_xor(part, 40, 64);
            float s48 = __shfl_xor(part, 48, 64);
            float s56 = __shfl_xor(part, 56, 64);
            float tmp = ((part + s08) + (s16 + s24)) + ((s32 + s40) + (s48 + s56));

            float y0 = 0.f, y1 = 0.f, y2 = 0.f, y3 = 0.f;
#pragma unroll
            for (int q = 0; q < 2; ++q) {
                float4 w4 = f.w[q], b4 = f.b[q], r4 = f.r[q];
                S[4*q+0] = fmaf(S[4*q+0], w4.x, fmaf(tmp, b4.x, vk[4*q+0]));
                y0 = fmaf(S[4*q+0], r4.x, y0);
                S[4*q+1] = fmaf(S[4*q+1], w4.y, fmaf(tmp, b4.y, vk[4*q+1]));
                y1 = fmaf(S[4*q+1], r4.y, y1);
                S[4*q+2] = fmaf(S[4*q+2], w4.z, fmaf(tmp, b4.z, vk[4*q+2]));
                y2 = fmaf(S[4*q+2], r4.z, y2);
                S[4*q+3] = fmaf(S[4*q+3], w4.w, fmaf(tmp, b4.w, vk[4*q+3]));
                y3 = fmaf(S[4*q+3], r4.w, y3);
            }
            // no cross-lane reduction: store this lane's bf16 partial
            yp8[ybase + t * CC] = f2bf((y0 + y1) + (y2 + y3));
        };

        loadfrag(f0, 0);
        loadfrag(f1, 1);
        loadfrag(f2, 2);

        int t = 0;
        for (; t + 2 < TT; t += 3) {
            stepf(f0, t);
            if (t + 3 < TT) loadfrag(f0, t + 3);
            stepf(f1, t + 1);
            if (t + 4 < TT) loadfrag(f1, t + 4);
            stepf(f2, t + 2);
            if (t + 5 < TT) loadfrag(f2, t + 5);
        }
        if (t < TT) stepf(f0, t);
        if (t + 1 < TT) stepf(f1, t + 1);
    } else {
        // gate_w2: gbuf(b,T,C) = (gw2(768x192) @ gh(b,192,T))^T
        const int gb = blk - 48;
        const int bx = gb & 31;
        const int rem = gb >> 5;            // 0..23
        const int by = rem % 12, bz = rem / 12;
        const float* Bm = gh + (size_t)bz * (192L * TT);
        float* Cm = gbuf + (size_t)bz * ((long)TT * CC);
        const int m0t = by * 64, n0t = bx * 64;

        const int mi = (tid & 15) * 4, ni = (tid >> 4) * 4;   // TOUT mapping
        float acc[4][4];
#pragma unroll
        for (int i = 0; i < 4; ++i)
#pragma unroll
            for (int j = 0; j < 4; ++j) acc[i][j] = 0.f;

        for (int k0 = 0; k0 < 192; k0 += 16) {
            {
                const int row = tid >> 2, kc = (tid & 3) * 4;
                float4 av = *(const float4*)&gw2[(size_t)(m0t + row) * 192 + k0 + kc];
                As[kc + 0][row] = av.x; As[kc + 1][row] = av.y;
                As[kc + 2][row] = av.z; As[kc + 3][row] = av.w;
            }
            {
                const int krow = tid >> 4, tc = (tid & 15) * 4;
                *(float4*)&Bs[krow][tc] = *(const float4*)&Bm[(size_t)(k0 + krow) * TT + n0t + tc];
            }
            __syncthreads();
#pragma unroll
            for (int kk = 0; kk < 16; ++kk) {
                float4 a4 = *(const float4*)&As[kk][mi];
                float4 b4 = *(const float4*)&Bs[kk][ni];
                float am[4] = {a4.x, a4.y, a4.z, a4.w};
                float bn[4] = {b4.x, b4.y, b4.z, b4.w};
#pragma unroll
                for (int i = 0; i < 4; ++i)
#pragma unroll
                    for (int j = 0; j < 4; ++j) acc[i][j] = fmaf(am[i], bn[j], acc[i][j]);
            }
            __syncthreads();
        }
        const int mbase = m0t + mi, nbase = n0t + ni;
#pragma unroll
        for (int j = 0; j < 4; ++j) {
            float4 o = {acc[0][j], acc[1][j], acc[2][j], acc[3][j]};
            *(float4*)&Cm[(size_t)(nbase + j) * CC + mbase] = o;
        }
    }
}

// ---------------------------------------------------------------------------
// E2: sum 8 bf16 y-partials, RMSNorm*lnw + (sum_head r*k*faaaa)*v, *g -> bf16 z
// ---------------------------------------------------------------------------
__global__ __launch_bounds__(256) void e2_kernel(
    const unsigned short* __restrict__ yp8, const float* __restrict__ rA,
    const float* __restrict__ kA, const float* __restrict__ vA,
    const float* __restrict__ gA, const float* __restrict__ faaaa,
    const float* __restrict__ lnw, unsigned short* __restrict__ zB)
{
    const int bt = blockIdx.x;
    const int b = bt / TT, t = bt - b * TT;
    const size_t base = (size_t)bt * CC;
    const int tid = threadIdx.x;
    const int wave = tid >> 6;
    __shared__ float red[4];
    __shared__ float rk[12];

    float yv[3];
    float ss = 0.f;
#pragma unroll
    for (int ch = 0; ch < 3; ++ch) {
        int c = ch * 256 + tid;
        float y = 0.f;
#pragma unroll
        for (int jg = 0; jg < 8; ++jg)
            y += bf2f(yp8[((size_t)(jg * BB + b) * TT + t) * CC + c]);
        yv[ch] = y;
        ss = fmaf(y, y, ss);
        float p = rA[base + c] * kA[base + c] * faaaa[c];
#pragma unroll
        for (int off = 32; off; off >>= 1) p += __shfl_xor(p, off, 64);
        if ((tid & 63) == 0) rk[ch * 4 + wave] = p;
    }
#pragma unroll
    for (int off = 32; off; off >>= 1) ss += __shfl_xor(ss, off, 64);
    if ((tid & 63) == 0) red[wave] = ss;
    __syncthreads();
    const float total = red[0] + red[1] + red[2] + red[3];
    const float scale = rsqrtf(total / (float)CC + 1e-5f);
#pragma unroll
    for (int ch = 0; ch < 3; ++ch) {
        int c = ch * 256 + tid;
        float out = yv[ch] * scale * lnw[c] + rk[c >> 6] * vA[base + c];
        zB[base + c] = f2bf(out * gA[base + c]);
    }
}

// ---------------------------------------------------------------------------
extern "C" void kernel_launch(void* const* d_in, const int* in_sizes, int n_in,
                              void* d_out, int out_size, void* d_ws, size_t ws_size,
                              hipStream_t stream)
{
    (void)in_sizes; (void)n_in; (void)out_size; (void)ws_size;
    const float* x        = (const float*)d_in[0];
    const float* tmaa_r   = (const float*)d_in[2];
    const float* tmaa_w   = (const float*)d_in[3];
    const float* tmaa_k   = (const float*)d_in[4];
    const float* tmaa_v   = (const float*)d_in[5];
    const float* tmaa_a   = (const float*)d_in[6];
    const float* tmaa_g   = (const float*)d_in[7];
    const float* tdecay   = (const float*)d_in[8];
    const float* tfaaaa   = (const float*)d_in[9];
    const float* taaaaa   = (const float*)d_in[10];
    const float* maa_w1   = (const float*)d_in[11];
    const float* maa_w2   = (const float*)d_in[12];
    const float* decay_w1 = (const float*)d_in[13];
    const float* decay_w2 = (const float*)d_in[14];
    const float* aaa_w1   = (const float*)d_in[15];
    const float* aaa_w2   = (const float*)d_in[16];
    const float* kkk_w1   = (const float*)d_in[17];
    const float* kkk_w2   = (const float*)d_in[18];
    const float* gate_w1  = (const float*)d_in[19];
    const float* gate_w2  = (const float*)d_in[20];
    const float* w_key    = (const float*)d_in[21];
    const float* w_value  = (const float*)d_in[22];
    const float* w_recept = (const float*)d_in[23];
    const float* w_output = (const float*)d_in[24];
    const float* lnw      = (const float*)d_in[25];
    float* out = (float*)d_out;

    float* ws   = (float*)d_ws;
    float* paux = ws;                 // 6*768
    float* tm   = ws + 8192;          // S1
    float* X6   = tm + S1;            // 6*FF
    float* dh   = X6 + 6 * FF;        // B*64*T = 262144
    float* ah   = dh + 262144;
    float* kh   = ah + 262144;
    float* gh   = kh + 262144;        // B*192*T = 786432
    float* gbuf = gh + 786432;        // FF
    // bf16 region
    unsigned short* yp8 = (unsigned short*)(gbuf + FF);  // 8*FF  (y partials)
    unsigned short* X6b = yp8 + 8 * FF;                  // 3*FF  (xr,xk,xv bf16 (C,T))
    unsigned short* zb  = X6b + 3 * FF;                  // FF
    unsigned short* wb  = zb + FF;                       // 5*294912
    unsigned short* xtb = wb + 5L * 294912;              // FF    (x bf16 (T,C))
    unsigned short* X6t = xtb + FF;                      // 3*FF  (xr,xk,xv bf16 (T,C))

    float* xw = X6 + 1 * FF; float* xk = X6 + 2 * FF;
    float* xa = X6 + 4 * FF; float* xg = X6 + 5 * FF;
    float* wwB = X6 + 0 * FF; float* rB  = X6 + 1 * FF; float* aaB = X6 + 2 * FF;
    float* b2B = X6 + 3 * FF; float* kB  = X6 + 4 * FF; float* vB  = X6 + 5 * FF;

    const long CT = (long)CC * TT;        // 1572864
    const long TC = (long)TT * CC;        // 1572864

    pack_aux_kernel<<<dim3(3), 256, 0, stream>>>(tmaa_r, tmaa_w, tmaa_k, tmaa_v, tmaa_a, tmaa_g, paux);
    wcvt_kernel<<<dim3(5760), 256, 0, stream>>>(w_recept, w_key, w_value, w_output, maa_w1, wb);
    xtr_kernel<<<dim3(32, 12, 2), 256, 0, stream>>>(x, xtb);

    // tm = tanh(maa_w1 @ x)  via bf16 MFMA
    maaw1_mfma_kernel<<<dim3(16, 3, 2), 256, 0, stream>>>(wb + 4L * 294912, xtb, tm);

    // X6[n] = x * (paux[n] + maa_w2[n]^T @ tm_n); bf16 side-write r/k/v;
    // fp32 store skipped for slots 0,3 (never read as fp32)
    gemm_kernel<1,0,0,2><<<dim3(32, 12, 12), 256, 0, stream>>>(
        maa_w2, tm, X6, paux, x,
        64, 768, TT, TT, 6,
        0, 64L * 768, 384L * TT, 64L * TT, CT, FF, 768, CT, X6b);

    // transpose bf16 conv inputs (C,T) -> (T,C)
    btr_kernel<<<dim3(32, 12, 6), 256, 0, stream>>>(X6b, X6t);

    // merged lora hiddens (decay/aaa/kkk/gate _w1, tanh)
    lorah_kernel<<<dim3(32, 3, 8), 256, 0, stream>>>(
        decay_w1, aaa_w1, kkk_w1, gate_w1, xw, xa, xk, xg, dh, ah, kh, gh);

    // merged 3 input convs via bf16 MFMA -> rB/kB/vB (fp32 (B,T,C))
    convs3_mfma_kernel<<<dim3(16, 3, 12), 256, 0, stream>>>(wb, X6t, X6);

    // lora outs -> (B,T,C)
    gemm_kernel<0,0,1,3><<<dim3(32, 12, 2), 256, 0, stream>>>(
        decay_w2, dh, wwB, tdecay, nullptr, 64, 64, TT, CC, 1,
        0, 0, 64L * TT, 0, TC, 0, 0, 0, nullptr);
    gemm_kernel<0,0,1,4><<<dim3(32, 12, 2), 256, 0, stream>>>(
        aaa_w2, ah, b2B /* a for now */, taaaaa, nullptr, 64, 64, TT, CC, 1,
        0, 0, 64L * TT, 0, TC, 0, 0, 0, nullptr);
    gemm_kernel<0,0,1,0><<<dim3(32, 12, 2), 256, 0, stream>>>(
        kkk_w2, kh, aaB /* kvec for now */, nullptr, nullptr, 64, 64, TT, CC, 1,
        0, 0, 64L * TT, 0, TC, 0, 0, 0, nullptr);

    // E1: build aa (over kvec slot) and b2 (over a slot)
    e1_kernel<<<dim3(BB * TT), 256, 0, stream>>>(kB, aaB, b2B);

    // WKV v10 (bf16 y-partials, no y reduction) + fused gate_w2 on idle CUs
    wkvgate_kernel<<<dim3(48 + 768), 256, 0, stream>>>(
        rB, wwB, kB, vB, aaB, b2B, yp8, gate_w2, gh, gbuf);

    // E2: sum partials + rmsnorm + faaaa bonus + gate -> bf16 z
    e2_kernel<<<dim3(BB * TT), 256, 0, stream>>>(yp8, rB, kB, vB, gbuf, tfaaaa, lnw, zb);

    // final grouped conv via bf16 MFMA: z (B,T,C) -> out (B,C,T)
    convout_mfma_kernel<<<dim3(16, 3, 4), 256, 0, stream>>>(wb + 3L * 294912, zb, out);
}

// Round 14
// 838.455 us; speedup vs baseline: 1.4274x; 1.4274x over previous
//
#include <hip/hip_runtime.h>
#include <math.h>

// Problem constants
#define BB 2
#define TT 2048
#define CC 768
#define HH 12
#define NN 64
#define GG 2
#define CG 384   // C/G
#define FF 3145728L   // B*C*T
#define S1 1572864L   // B*384*T

typedef __attribute__((ext_vector_type(8))) short bf8frag;   // 8 bf16 (4 VGPRs)
typedef __attribute__((ext_vector_type(4))) float f4acc;     // 4 fp32 acc

__device__ inline unsigned short f2bf(float x) {
    union { float f; unsigned u; } v; v.f = x;
    unsigned r = v.u + 0x7FFFu + ((v.u >> 16) & 1u);   // RNE
    return (unsigned short)(r >> 16);
}
__device__ inline float bf2f(unsigned short u) {
    union { unsigned u; float f; } v; v.u = ((unsigned)u) << 16;
    return v.f;
}

// ---------------------------------------------------------------------------
// Generic fp32 tiled GEMM v1: 64x64 tile, 256 threads, 4x4 micro-tile.
// bfout: optional bf16 side-write (mix GEMM emits bf16 xr/xk/xv copies).
// MODE==2: fp32 store skipped for zi in {0,3} (xr/xv fp32 never read).
// ---------------------------------------------------------------------------
template<int ATRANS, int BTRANS, int TOUT, int MODE>
__global__ __launch_bounds__(256) void gemm_kernel(
    const float* __restrict__ A, const float* __restrict__ Bm, float* __restrict__ Cm,
    const float* __restrict__ aux, const float* __restrict__ aux2,
    int K, int ldA, int ldB, int ldC, int zInner,
    long sA_o, long sA_i, long sB_o, long sB_i, long sC_o, long sC_i,
    long sAux_i, long sAux2_o, unsigned short* bfout)
{
    const int zo = blockIdx.z / zInner;
    const int zi = blockIdx.z % zInner;
    A  += (size_t)zo * sA_o + (size_t)zi * sA_i;
    Bm += (size_t)zo * sB_o + (size_t)zi * sB_i;
    Cm += (size_t)zo * sC_o + (size_t)zi * sC_i;
    if (MODE == 2) { aux += (size_t)zi * sAux_i; aux2 += (size_t)zo * sAux2_o; }

    const int m0t = blockIdx.y * 64;
    const int n0t = blockIdx.x * 64;
    const int tid = threadIdx.x;

    __shared__ float As[16][64];
    __shared__ float Bs[16][64];

    int mi, ni;
    if (TOUT) { mi = (tid & 15) * 4; ni = (tid >> 4) * 4; }
    else      { ni = (tid & 15) * 4; mi = (tid >> 4) * 4; }

    float acc[4][4];
#pragma unroll
    for (int i = 0; i < 4; ++i)
#pragma unroll
        for (int j = 0; j < 4; ++j) acc[i][j] = 0.f;

    for (int k0 = 0; k0 < K; k0 += 16) {
        if (!ATRANS) {
            const int row = tid >> 2;
            const int kc  = (tid & 3) * 4;
            float4 av = *(const float4*)&A[(size_t)(m0t + row) * ldA + k0 + kc];
            As[kc + 0][row] = av.x; As[kc + 1][row] = av.y;
            As[kc + 2][row] = av.z; As[kc + 3][row] = av.w;
        } else {
            const int krow = tid >> 4;
            const int mc   = (tid & 15) * 4;
            *(float4*)&As[krow][mc] = *(const float4*)&A[(size_t)(k0 + krow) * ldA + m0t + mc];
        }
        if (!BTRANS) {
            const int krow = tid >> 4;
            const int tc   = (tid & 15) * 4;
            *(float4*)&Bs[krow][tc] = *(const float4*)&Bm[(size_t)(k0 + krow) * ldB + n0t + tc];
        } else {
            const int trow = tid >> 2;
            const int kc   = (tid & 3) * 4;
            float4 bv = *(const float4*)&Bm[(size_t)(n0t + trow) * ldB + k0 + kc];
            Bs[kc + 0][trow] = bv.x; Bs[kc + 1][trow] = bv.y;
            Bs[kc + 2][trow] = bv.z; Bs[kc + 3][trow] = bv.w;
        }
        __syncthreads();
#pragma unroll
        for (int kk = 0; kk < 16; ++kk) {
            float4 a4 = *(const float4*)&As[kk][mi];
            float4 b4 = *(const float4*)&Bs[kk][ni];
            float am[4] = {a4.x, a4.y, a4.z, a4.w};
            float bn[4] = {b4.x, b4.y, b4.z, b4.w};
#pragma unroll
            for (int i = 0; i < 4; ++i)
#pragma unroll
                for (int j = 0; j < 4; ++j) acc[i][j] = fmaf(am[i], bn[j], acc[i][j]);
        }
        __syncthreads();
    }

    const int mbase = m0t + mi, nbase = n0t + ni;
#pragma unroll
    for (int i = 0; i < 4; ++i) {
        float4 xv;
        if (MODE == 2) xv = *(const float4*)&aux2[(size_t)(mbase + i) * ldC + nbase];
        float xa[4] = {0.f, 0.f, 0.f, 0.f};
        if (MODE == 2) { xa[0] = xv.x; xa[1] = xv.y; xa[2] = xv.z; xa[3] = xv.w; }
#pragma unroll
        for (int j = 0; j < 4; ++j) {
            float v = acc[i][j];
            if (MODE == 1) v = tanhf(v);
            else if (MODE == 2) v = xa[j] * (aux[mbase + i] + v);
            else if (MODE == 3) {
                float u  = aux[mbase + i] + v;
                float sp = fmaxf(-u, 0.f) + log1pf(expf(-fabsf(u)));  // softplus(-u)
                float wl = -sp - 0.5f;
                v = expf(-expf(wl));
            } else if (MODE == 4) {
                float u = aux[mbase + i] + v;
                v = 1.f / (1.f + expf(-u));
            }
            acc[i][j] = v;
        }
    }
    if (!TOUT) {
        const bool skipf = (MODE == 2) && (bfout != nullptr) && (zi == 0 || zi == 3);
        if (!skipf) {
#pragma unroll
            for (int i = 0; i < 4; ++i) {
                float4 o = {acc[i][0], acc[i][1], acc[i][2], acc[i][3]};
                *(float4*)&Cm[(size_t)(mbase + i) * ldC + nbase] = o;
            }
        }
        // bf16 side-write for MFMA conv inputs: slots n in {0:xr, 2:xk, 3:xv}
        if (MODE == 2 && bfout != nullptr) {
            int sidx = (zi == 0) ? 0 : (zi == 2) ? 1 : (zi == 3) ? 2 : -1;
            if (sidx >= 0) {
                unsigned short* bp = bfout + (size_t)sidx * FF + (size_t)zo * ((long)CC * TT);
#pragma unroll
                for (int i = 0; i < 4; ++i) {
                    ushort4 o = {f2bf(acc[i][0]), f2bf(acc[i][1]), f2bf(acc[i][2]), f2bf(acc[i][3])};
                    *(ushort4*)&bp[(size_t)(mbase + i) * ldC + nbase] = o;
                }
            }
        }
    } else {
#pragma unroll
        for (int j = 0; j < 4; ++j) {
            float4 o = {acc[0][j], acc[1][j], acc[2][j], acc[3][j]};
            *(float4*)&Cm[(size_t)(nbase + j) * ldC + mbase] = o;
        }
    }
}

// ---------------------------------------------------------------------------
// Merged lora-hidden GEMMs (decay/aaa/kkk/gate _w1): tanh(W @ x_slot).
// grid (32,3,8): z = which*2 + b; which<3 uses only blockIdx.y==0 (M=64).
// ---------------------------------------------------------------------------
__global__ __launch_bounds__(256) void lorah_kernel(
    const float* __restrict__ w0, const float* __restrict__ w1,
    const float* __restrict__ w2, const float* __restrict__ w3,
    const float* __restrict__ x0, const float* __restrict__ x1,
    const float* __restrict__ x2, const float* __restrict__ x3,
    float* __restrict__ o0, float* __restrict__ o1,
    float* __restrict__ o2, float* __restrict__ o3)
{
    const int z = blockIdx.z;
    const int which = z >> 1, bz = z & 1;
    if (which < 3 && blockIdx.y > 0) return;
    const float* A; const float* Bm; float* Cm; int M;
    if (which == 0)      { A = w0; Bm = x0; Cm = o0; M = 64; }
    else if (which == 1) { A = w1; Bm = x1; Cm = o1; M = 64; }
    else if (which == 2) { A = w2; Bm = x2; Cm = o2; M = 64; }
    else                 { A = w3; Bm = x3; Cm = o3; M = 192; }
    Bm += (size_t)bz * ((long)CC * TT);
    Cm += (size_t)bz * ((long)M * TT);

    const int m0t = blockIdx.y * 64;
    const int n0t = blockIdx.x * 64;
    const int tid = threadIdx.x;

    __shared__ float As[16][64];
    __shared__ float Bs[16][64];

    const int ni = (tid & 15) * 4, mi = (tid >> 4) * 4;
    float acc[4][4];
#pragma unroll
    for (int i = 0; i < 4; ++i)
#pragma unroll
        for (int j = 0; j < 4; ++j) acc[i][j] = 0.f;

    for (int k0 = 0; k0 < CC; k0 += 16) {
        {
            const int row = tid >> 2, kc = (tid & 3) * 4;
            float4 av = *(const float4*)&A[(size_t)(m0t + row) * CC + k0 + kc];
            As[kc + 0][row] = av.x; As[kc + 1][row] = av.y;
            As[kc + 2][row] = av.z; As[kc + 3][row] = av.w;
        }
        {
            const int krow = tid >> 4, tc = (tid & 15) * 4;
            *(float4*)&Bs[krow][tc] = *(const float4*)&Bm[(size_t)(k0 + krow) * TT + n0t + tc];
        }
        __syncthreads();
#pragma unroll
        for (int kk = 0; kk < 16; ++kk) {
            float4 a4 = *(const float4*)&As[kk][mi];
            float4 b4 = *(const float4*)&Bs[kk][ni];
            float am[4] = {a4.x, a4.y, a4.z, a4.w};
            float bn[4] = {b4.x, b4.y, b4.z, b4.w};
#pragma unroll
            for (int i = 0; i < 4; ++i)
#pragma unroll
                for (int j = 0; j < 4; ++j) acc[i][j] = fmaf(am[i], bn[j], acc[i][j]);
        }
        __syncthreads();
    }
    const int mbase = m0t + mi, nbase = n0t + ni;
#pragma unroll
    for (int i = 0; i < 4; ++i) {
        float4 o = {tanhf(acc[i][0]), tanhf(acc[i][1]), tanhf(acc[i][2]), tanhf(acc[i][3])};
        *(float4*)&Cm[(size_t)(mbase + i) * TT + nbase] = o;
    }
}

// ---------------------------------------------------------------------------
// Merged 3 input convs via bf16 MFMA: grid (16,3,12), z = conv*4 + b*2 + g.
// ---------------------------------------------------------------------------
__global__ __launch_bounds__(256) void convs3_mfma_kernel(
    const unsigned short* __restrict__ wball, const unsigned short* __restrict__ X6t,
    float* __restrict__ X6)
{
    const int z = blockIdx.z;
    const int conv = z >> 2, bg = z & 3, b = bg >> 1, g = bg & 1;
    const unsigned short* Wb = wball + (size_t)conv * 294912;
    const unsigned short* Xb = X6t + (size_t)conv * FF;
    const int oslot = (conv == 0) ? 1 : (conv == 1) ? 4 : 5;
    float* Cout = X6 + (size_t)oslot * FF;

    const int t0 = blockIdx.x * 128;
    const int m0 = blockIdx.y * 128;
    const int tid = threadIdx.x;
    const int wave = tid >> 6, lane = tid & 63;
    const int lq = lane >> 4, lr = lane & 15;

    __shared__ unsigned short Ws[128 * 40];
    __shared__ unsigned short Xs[128 * 40];

    const unsigned short* Wg = Wb + (size_t)g * (CG * CG);
    const long xbase = (long)b * (long)TT * CC;

    f4acc acc0[8], acc1[8];
#pragma unroll
    for (int j = 0; j < 8; ++j) { acc0[j] = (f4acc)0.f; acc1[j] = (f4acc)0.f; }

    for (int k0 = 0; k0 < CG; k0 += 32) {
        {
            const int m = tid >> 1, kc = (tid & 1) * 16;
            const unsigned short* src = Wg + (size_t)(m0 + m) * CG + k0 + kc;
            *(bf8frag*)&Ws[m * 40 + kc]     = *(const bf8frag*)src;
            *(bf8frag*)&Ws[m * 40 + kc + 8] = *(const bf8frag*)(src + 8);
        }
        {
            const int t = tid >> 1, kc = (tid & 1) * 16;
            const unsigned short* src = Xb + xbase + (long)(t0 + t) * CC + g * CG + k0 + kc;
            *(bf8frag*)&Xs[t * 40 + kc]     = *(const bf8frag*)src;
            *(bf8frag*)&Xs[t * 40 + kc + 8] = *(const bf8frag*)(src + 8);
        }
        __syncthreads();

        bf8frag a0 = *(const bf8frag*)&Ws[(32 * wave + lr) * 40 + lq * 8];
        bf8frag a1 = *(const bf8frag*)&Ws[(32 * wave + 16 + lr) * 40 + lq * 8];
#pragma unroll
        for (int nj = 0; nj < 8; ++nj) {
            bf8frag bb = *(const bf8frag*)&Xs[(16 * nj + lr) * 40 + lq * 8];
            acc0[nj] = __builtin_amdgcn_mfma_f32_16x16x32_bf16(a0, bb, acc0[nj], 0, 0, 0);
            acc1[nj] = __builtin_amdgcn_mfma_f32_16x16x32_bf16(a1, bb, acc1[nj], 0, 0, 0);
        }
        __syncthreads();
    }

#pragma unroll
    for (int fi = 0; fi < 2; ++fi) {
        const int cbase = m0 + 32 * wave + 16 * fi + lq * 4;
#pragma unroll
        for (int nj = 0; nj < 8; ++nj) {
            const f4acc av = fi ? acc1[nj] : acc0[nj];
            const int t = t0 + 16 * nj + lr;
            float4 o = {av[0], av[1], av[2], av[3]};
            *(float4*)&Cout[(long)b * (long)TT * CC + (long)t * CC + g * CG + cbase] = o;
        }
    }
}

// ---------------------------------------------------------------------------
// Output conv via bf16 MFMA: z (B,T,C) bf16 -> out (B,C,T) fp32.
// ---------------------------------------------------------------------------
__global__ __launch_bounds__(256) void convout_mfma_kernel(
    const unsigned short* __restrict__ Wb, const unsigned short* __restrict__ Xb,
    float* __restrict__ Cout)
{
    const int bz = blockIdx.z; const int b = bz >> 1, g = bz & 1;
    const int t0 = blockIdx.x * 128;
    const int m0 = blockIdx.y * 128;
    const int tid = threadIdx.x;
    const int wave = tid >> 6, lane = tid & 63;
    const int lq = lane >> 4, lr = lane & 15;

    __shared__ unsigned short Ws[128 * 40];
    __shared__ unsigned short Xs[128 * 40];

    const unsigned short* Wg = Wb + (size_t)g * (CG * CG);
    const long xbase = (long)b * (long)TT * CC;

    f4acc acc0[8], acc1[8];
#pragma unroll
    for (int j = 0; j < 8; ++j) { acc0[j] = (f4acc)0.f; acc1[j] = (f4acc)0.f; }

    for (int k0 = 0; k0 < CG; k0 += 32) {
        {
            const int m = tid >> 1, kc = (tid & 1) * 16;
            const unsigned short* src = Wg + (size_t)(m0 + m) * CG + k0 + kc;
            *(bf8frag*)&Ws[m * 40 + kc]     = *(const bf8frag*)src;
            *(bf8frag*)&Ws[m * 40 + kc + 8] = *(const bf8frag*)(src + 8);
        }
        {
            const int t = tid >> 1, kc = (tid & 1) * 16;
            const unsigned short* src = Xb + xbase + (long)(t0 + t) * CC + g * CG + k0 + kc;
            *(bf8frag*)&Xs[t * 40 + kc]     = *(const bf8frag*)src;
            *(bf8frag*)&Xs[t * 40 + kc + 8] = *(const bf8frag*)(src + 8);
        }
        __syncthreads();

        bf8frag a0 = *(const bf8frag*)&Ws[(32 * wave + lr) * 40 + lq * 8];
        bf8frag a1 = *(const bf8frag*)&Ws[(32 * wave + 16 + lr) * 40 + lq * 8];
#pragma unroll
        for (int nj = 0; nj < 8; ++nj) {
            bf8frag bb = *(const bf8frag*)&Xs[(16 * nj + lr) * 40 + lq * 8];
            acc0[nj] = __builtin_amdgcn_mfma_f32_16x16x32_bf16(a0, bb, acc0[nj], 0, 0, 0);
            acc1[nj] = __builtin_amdgcn_mfma_f32_16x16x32_bf16(a1, bb, acc1[nj], 0, 0, 0);
        }
        __syncthreads();
    }

#pragma unroll
    for (int fi = 0; fi < 2; ++fi) {
        const int cbase = m0 + 32 * wave + 16 * fi + lq * 4;
#pragma unroll
        for (int nj = 0; nj < 8; ++nj) {
            const f4acc av = fi ? acc1[nj] : acc0[nj];
            const int t = t0 + 16 * nj + lr;
#pragma unroll
            for (int i = 0; i < 4; ++i)
                Cout[(long)b * (long)CC * TT + (long)(g * CG + cbase + i) * TT + t] = av[i];
        }
    }
}

// ---------------------------------------------------------------------------
// maa_w1 bf16 MFMA GEMM: tm(b,384,T) = tanh( W(384x768) @ x(b,768,T) ).
// ---------------------------------------------------------------------------
__global__ __launch_bounds__(256) void maaw1_mfma_kernel(
    const unsigned short* __restrict__ Wb, const unsigned short* __restrict__ Xb,
    float* __restrict__ Cout)
{
    const int b = blockIdx.z;
    const int t0 = blockIdx.x * 128;
    const int m0 = blockIdx.y * 128;
    const int tid = threadIdx.x;
    const int wave = tid >> 6, lane = tid & 63;
    const int lq = lane >> 4, lr = lane & 15;

    __shared__ unsigned short Ws[128 * 40];
    __shared__ unsigned short Xs[128 * 40];

    const long xbase = (long)b * (long)TT * CC;

    f4acc acc0[8], acc1[8];
#pragma unroll
    for (int j = 0; j < 8; ++j) { acc0[j] = (f4acc)0.f; acc1[j] = (f4acc)0.f; }

    for (int k0 = 0; k0 < CC; k0 += 32) {
        {
            const int m = tid >> 1, kc = (tid & 1) * 16;
            const unsigned short* src = Wb + (size_t)(m0 + m) * CC + k0 + kc;
            *(bf8frag*)&Ws[m * 40 + kc]     = *(const bf8frag*)src;
            *(bf8frag*)&Ws[m * 40 + kc + 8] = *(const bf8frag*)(src + 8);
        }
        {
            const int t = tid >> 1, kc = (tid & 1) * 16;
            const unsigned short* src = Xb + xbase + (long)(t0 + t) * CC + k0 + kc;
            *(bf8frag*)&Xs[t * 40 + kc]     = *(const bf8frag*)src;
            *(bf8frag*)&Xs[t * 40 + kc + 8] = *(const bf8frag*)(src + 8);
        }
        __syncthreads();

        bf8frag a0 = *(const bf8frag*)&Ws[(32 * wave + lr) * 40 + lq * 8];
        bf8frag a1 = *(const bf8frag*)&Ws[(32 * wave + 16 + lr) * 40 + lq * 8];
#pragma unroll
        for (int nj = 0; nj < 8; ++nj) {
            bf8frag bb = *(const bf8frag*)&Xs[(16 * nj + lr) * 40 + lq * 8];
            acc0[nj] = __builtin_amdgcn_mfma_f32_16x16x32_bf16(a0, bb, acc0[nj], 0, 0, 0);
            acc1[nj] = __builtin_amdgcn_mfma_f32_16x16x32_bf16(a1, bb, acc1[nj], 0, 0, 0);
        }
        __syncthreads();
    }

#pragma unroll
    for (int fi = 0; fi < 2; ++fi) {
        const int m = m0 + 32 * wave + 16 * fi + lq * 4;
#pragma unroll
        for (int nj = 0; nj < 8; ++nj) {
            const f4acc av = fi ? acc1[nj] : acc0[nj];
            const int t = t0 + 16 * nj + lr;
#pragma unroll
            for (int i = 0; i < 4; ++i)
                Cout[(long)b * 384 * TT + (long)(m + i) * TT + t] = tanhf(av[i]);
        }
    }
}

// ---------------------------------------------------------------------------
// Transpose kernels (LDS 64x64 tiles)
// ---------------------------------------------------------------------------
__global__ __launch_bounds__(256) void xtr_kernel(const float* __restrict__ xin,
                                                  unsigned short* __restrict__ xout)
{
    __shared__ unsigned short L[64][68];
    const int t0 = blockIdx.x * 64, c0 = blockIdx.y * 64, b = blockIdx.z;
    const int tid = threadIdx.x;
    const int lr = tid >> 4, lc = (tid & 15) * 4;
#pragma unroll
    for (int i = 0; i < 4; ++i) {
        int c = lr + i * 16;
        float4 v = *(const float4*)&xin[(size_t)b * CC * TT + (size_t)(c0 + c) * TT + t0 + lc];
        L[c][lc + 0] = f2bf(v.x); L[c][lc + 1] = f2bf(v.y);
        L[c][lc + 2] = f2bf(v.z); L[c][lc + 3] = f2bf(v.w);
    }
    __syncthreads();
#pragma unroll
    for (int i = 0; i < 4; ++i) {
        int t = lr + i * 16;
        ushort4 o = {L[lc + 0][t], L[lc + 1][t], L[lc + 2][t], L[lc + 3][t]};
        *(ushort4*)&xout[(size_t)b * TT * CC + (size_t)(t0 + t) * CC + c0 + lc] = o;
    }
}

__global__ __launch_bounds__(256) void btr_kernel(const unsigned short* __restrict__ xin,
                                                  unsigned short* __restrict__ xout)
{
    __shared__ unsigned short L[64][68];
    const int t0 = blockIdx.x * 64, c0 = blockIdx.y * 64;
    const int s = blockIdx.z >> 1, b = blockIdx.z & 1;
    const int tid = threadIdx.x;
    const int lr = tid >> 4, lc = (tid & 15) * 4;
    const size_t ibase = (size_t)s * FF + (size_t)b * CC * TT;
    const size_t obase = (size_t)s * FF + (size_t)b * TT * CC;
#pragma unroll
    for (int i = 0; i < 4; ++i) {
        int c = lr + i * 16;
        ushort4 v = *(const ushort4*)&xin[ibase + (size_t)(c0 + c) * TT + t0 + lc];
        L[c][lc + 0] = v.x; L[c][lc + 1] = v.y; L[c][lc + 2] = v.z; L[c][lc + 3] = v.w;
    }
    __syncthreads();
#pragma unroll
    for (int i = 0; i < 4; ++i) {
        int t = lr + i * 16;
        ushort4 o = {L[lc + 0][t], L[lc + 1][t], L[lc + 2][t], L[lc + 3][t]};
        *(ushort4*)&xout[obase + (size_t)(t0 + t) * CC + c0 + lc] = o;
    }
}

// ---------------------------------------------------------------------------
__global__ void wcvt_kernel(const float* __restrict__ w0, const float* __restrict__ w1,
                            const float* __restrict__ w2, const float* __restrict__ w3,
                            const float* __restrict__ w4, unsigned short* __restrict__ wb)
{
    const int i = blockIdx.x * 256 + threadIdx.x;   // total 5*294912
    const int which = i / 294912, r = i - which * 294912;
    const float* s = (which == 0) ? w0 : (which == 1) ? w1 : (which == 2) ? w2
                   : (which == 3) ? w3 : w4;
    wb[i] = f2bf(s[r]);
}

// ---------------------------------------------------------------------------
__global__ void pack_aux_kernel(const float* __restrict__ r, const float* __restrict__ w,
                                const float* __restrict__ k, const float* __restrict__ v,
                                const float* __restrict__ a, const float* __restrict__ g,
                                float* __restrict__ paux)
{
    int c = blockIdx.x * blockDim.x + threadIdx.x;
    if (c < CC) {
        paux[0 * CC + c] = 1.f + r[c];
        paux[1 * CC + c] = 1.f + w[c];
        paux[2 * CC + c] = 1.f + k[c];
        paux[3 * CC + c] = 1.f + v[c];
        paux[4 * CC + c] = 1.f + a[c];
        paux[5 * CC + c] = 1.f + g[c];
    }
}

// ---------------------------------------------------------------------------
// E1: per token, kk = k + kvec; per-head L2-normalize; aa=-kkn, b2=kkn*a.
// ---------------------------------------------------------------------------
__global__ __launch_bounds__(256) void e1_kernel(const float* __restrict__ kA,
                                                 float* __restrict__ kvecA,
                                                 float* __restrict__ aA)
{
    const size_t base = (size_t)blockIdx.x * CC;
    const int tid = threadIdx.x;
#pragma unroll
    for (int ch = 0; ch < 3; ++ch) {
        int c = ch * 256 + tid;
        float kk = kA[base + c] + kvecA[base + c];
        float ss = kk * kk;
#pragma unroll
        for (int off = 32; off; off >>= 1) ss += __shfl_xor(ss, off, 64);
        float denom = fmaxf(sqrtf(ss), 1e-12f);
        float kkn = kk / denom;
        float av = aA[base + c];
        kvecA[base + c] = -kkn;       // aa
        aA[base + c]    = kkn * av;   // b2
    }
}

// ---------------------------------------------------------------------------
// WKV-7 v11 = v9 packaging (1 wave/block, 192 blocks, blk = rg*24+bh XCD
// swizzle, SADDR addressing, 3-deep named-fragment prefetch) + v10's y-
// reduction deletion ONLY: each lane stores its bf16 partial to its jg plane
// (8 lanes x 16B contiguous per plane per step); e2 sums the 8 planes.
// Round-13's 4-wave/block repackaging quadrupled per-CU VMEM issue — reverted.
// ---------------------------------------------------------------------------
struct WFrag {
    float4 w[2], a[2], b[2], k[2], r[2];
    float vv;
};

__global__ __launch_bounds__(64) void wkv_kernel(
    const float* __restrict__ rA, const float* __restrict__ wA,
    const float* __restrict__ kA, const float* __restrict__ vA,
    const float* __restrict__ aaA, const float* __restrict__ b2A,
    unsigned short* __restrict__ yp8)
{
    const int blk = blockIdx.x;          // rg*24 + bh  (XCD swizzle)
    const int bh = blk % 24, rg = blk / 24;
    const int b = bh / HH, h = bh - b * HH;
    const int lane = threadIdx.x;
    const int jg = lane >> 3, p = lane & 7;
    const int row = rg * 8 + p;
    const int base = b * TT * CC + h * NN;
    const int fo = jg * 8;
    const int ybase = (jg * BB + b) * (TT * CC) + h * NN + row;

    float S[8];
#pragma unroll
    for (int i = 0; i < 8; ++i) S[i] = 0.f;

    WFrag f0, f1, f2;

    auto loadfrag = [&](WFrag& f, int t) {
        const int o = base + t * CC + fo;
#pragma unroll
        for (int q = 0; q < 2; ++q) {
            f.w[q] = *(const float4*)&wA[o + 4 * q];
            f.a[q] = *(const float4*)&aaA[o + 4 * q];
            f.b[q] = *(const float4*)&b2A[o + 4 * q];
            f.k[q] = *(const float4*)&kA[o + 4 * q];
            f.r[q] = *(const float4*)&rA[o + 4 * q];
        }
        f.vv = vA[base + t * CC + row];
    };

    auto stepf = [&](const WFrag& f, int t) {
        const float vv = f.vv;
        float vk[8];
#pragma unroll
        for (int q = 0; q < 2; ++q) {
            vk[4*q+0] = vv * f.k[q].x;
            vk[4*q+1] = vv * f.k[q].y;
            vk[4*q+2] = vv * f.k[q].z;
            vk[4*q+3] = vv * f.k[q].w;
        }

        float t0 = 0.f, t1 = 0.f, t2 = 0.f, t3 = 0.f;
#pragma unroll
        for (int q = 0; q < 2; ++q) {
            float4 a4 = f.a[q];
            t0 = fmaf(S[4*q+0], a4.x, t0);
            t1 = fmaf(S[4*q+1], a4.y, t1);
            t2 = fmaf(S[4*q+2], a4.z, t2);
            t3 = fmaf(S[4*q+3], a4.w, t3);
        }
        float part = (t0 + t1) + (t2 + t3);
        float s08 = __shfl_xor(part,  8, 64);
        float s16 = __shfl_xor(part, 16, 64);
        float s24 = __shfl_xor(part, 24, 64);
        float s32 = __shfl_xor(part, 32, 64);
        float s40 = __shfl_xor(part, 40, 64);
        float s48 = __shfl_xor(part, 48, 64);
        float s56 = __shfl_xor(part, 56, 64);
        float tmp = ((part + s08) + (s16 + s24)) + ((s32 + s40) + (s48 + s56));

        float y0 = 0.f, y1 = 0.f, y2 = 0.f, y3 = 0.f;
#pragma unroll
        for (int q = 0; q < 2; ++q) {
            float4 w4 = f.w[q], b4 = f.b[q], r4 = f.r[q];
            S[4*q+0] = fmaf(S[4*q+0], w4.x, fmaf(tmp, b4.x, vk[4*q+0]));
            y0 = fmaf(S[4*q+0], r4.x, y0);
            S[4*q+1] = fmaf(S[4*q+1], w4.y, fmaf(tmp, b4.y, vk[4*q+1]));
            y1 = fmaf(S[4*q+1], r4.y, y1);
            S[4*q+2] = fmaf(S[4*q+2], w4.z, fmaf(tmp, b4.z, vk[4*q+2]));
            y2 = fmaf(S[4*q+2], r4.z, y2);
            S[4*q+3] = fmaf(S[4*q+3], w4.w, fmaf(tmp, b4.w, vk[4*q+3]));
            y3 = fmaf(S[4*q+3], r4.w, y3);
        }
        // no cross-lane y reduction: store this lane's bf16 partial
        yp8[ybase + t * CC] = f2bf((y0 + y1) + (y2 + y3));
    };

    loadfrag(f0, 0);
    loadfrag(f1, 1);
    loadfrag(f2, 2);

    int t = 0;
    for (; t + 2 < TT; t += 3) {
        stepf(f0, t);
        if (t + 3 < TT) loadfrag(f0, t + 3);
        stepf(f1, t + 1);
        if (t + 4 < TT) loadfrag(f1, t + 4);
        stepf(f2, t + 2);
        if (t + 5 < TT) loadfrag(f2, t + 5);
    }
    if (t < TT) stepf(f0, t);
    if (t + 1 < TT) stepf(f1, t + 1);
}

// ---------------------------------------------------------------------------
// E2: sum 8 bf16 y-partials, RMSNorm*lnw + (sum_head r*k*faaaa)*v, *g -> bf16 z
// ---------------------------------------------------------------------------
__global__ __launch_bounds__(256) void e2_kernel(
    const unsigned short* __restrict__ yp8, const float* __restrict__ rA,
    const float* __restrict__ kA, const float* __restrict__ vA,
    const float* __restrict__ gA, const float* __restrict__ faaaa,
    const float* __restrict__ lnw, unsigned short* __restrict__ zB)
{
    const int bt = blockIdx.x;
    const int b = bt / TT, t = bt - b * TT;
    const size_t base = (size_t)bt * CC;
    const int tid = threadIdx.x;
    const int wave = tid >> 6;
    __shared__ float red[4];
    __shared__ float rk[12];

    float yv[3];
    float ss = 0.f;
#pragma unroll
    for (int ch = 0; ch < 3; ++ch) {
        int c = ch * 256 + tid;
        float y = 0.f;
#pragma unroll
        for (int jg = 0; jg < 8; ++jg)
            y += bf2f(yp8[((size_t)(jg * BB + b) * TT + t) * CC + c]);
        yv[ch] = y;
        ss = fmaf(y, y, ss);
        float p = rA[base + c] * kA[base + c] * faaaa[c];
#pragma unroll
        for (int off = 32; off; off >>= 1) p += __shfl_xor(p, off, 64);
        if ((tid & 63) == 0) rk[ch * 4 + wave] = p;
    }
#pragma unroll
    for (int off = 32; off; off >>= 1) ss += __shfl_xor(ss, off, 64);
    if ((tid & 63) == 0) red[wave] = ss;
    __syncthreads();
    const float total = red[0] + red[1] + red[2] + red[3];
    const float scale = rsqrtf(total / (float)CC + 1e-5f);
#pragma unroll
    for (int ch = 0; ch < 3; ++ch) {
        int c = ch * 256 + tid;
        float out = yv[ch] * scale * lnw[c] + rk[c >> 6] * vA[base + c];
        zB[base + c] = f2bf(out * gA[base + c]);
    }
}

// ---------------------------------------------------------------------------
extern "C" void kernel_launch(void* const* d_in, const int* in_sizes, int n_in,
                              void* d_out, int out_size, void* d_ws, size_t ws_size,
                              hipStream_t stream)
{
    (void)in_sizes; (void)n_in; (void)out_size; (void)ws_size;
    const float* x        = (const float*)d_in[0];
    const float* tmaa_r   = (const float*)d_in[2];
    const float* tmaa_w   = (const float*)d_in[3];
    const float* tmaa_k   = (const float*)d_in[4];
    const float* tmaa_v   = (const float*)d_in[5];
    const float* tmaa_a   = (const float*)d_in[6];
    const float* tmaa_g   = (const float*)d_in[7];
    const float* tdecay   = (const float*)d_in[8];
    const float* tfaaaa   = (const float*)d_in[9];
    const float* taaaaa   = (const float*)d_in[10];
    const float* maa_w1   = (const float*)d_in[11];
    const float* maa_w2   = (const float*)d_in[12];
    const float* decay_w1 = (const float*)d_in[13];
    const float* decay_w2 = (const float*)d_in[14];
    const float* aaa_w1   = (const float*)d_in[15];
    const float* aaa_w2   = (const float*)d_in[16];
    const float* kkk_w1   = (const float*)d_in[17];
    const float* kkk_w2   = (const float*)d_in[18];
    const float* gate_w1  = (const float*)d_in[19];
    const float* gate_w2  = (const float*)d_in[20];
    const float* w_key    = (const float*)d_in[21];
    const float* w_value  = (const float*)d_in[22];
    const float* w_recept = (const float*)d_in[23];
    const float* w_output = (const float*)d_in[24];
    const float* lnw      = (const float*)d_in[25];
    float* out = (float*)d_out;

    float* ws   = (float*)d_ws;
    float* paux = ws;                 // 6*768
    float* tm   = ws + 8192;          // S1
    float* X6   = tm + S1;            // 6*FF
    float* dh   = X6 + 6 * FF;        // B*64*T = 262144
    float* ah   = dh + 262144;
    float* kh   = ah + 262144;
    float* gh   = kh + 262144;        // B*192*T = 786432
    float* gbuf = gh + 786432;        // FF
    // bf16 region
    unsigned short* yp8 = (unsigned short*)(gbuf + FF);  // 8*FF  (y partials)
    unsigned short* X6b = yp8 + 8 * FF;                  // 3*FF  (xr,xk,xv bf16 (C,T))
    unsigned short* zb  = X6b + 3 * FF;                  // FF
    unsigned short* wb  = zb + FF;                       // 5*294912
    unsigned short* xtb = wb + 5L * 294912;              // FF    (x bf16 (T,C))
    unsigned short* X6t = xtb + FF;                      // 3*FF  (xr,xk,xv bf16 (T,C))

    float* xw = X6 + 1 * FF; float* xk = X6 + 2 * FF;
    float* xa = X6 + 4 * FF; float* xg = X6 + 5 * FF;
    float* wwB = X6 + 0 * FF; float* rB  = X6 + 1 * FF; float* aaB = X6 + 2 * FF;
    float* b2B = X6 + 3 * FF; float* kB  = X6 + 4 * FF; float* vB  = X6 + 5 * FF;

    const long CT = (long)CC * TT;        // 1572864
    const long TC = (long)TT * CC;        // 1572864

    pack_aux_kernel<<<dim3(3), 256, 0, stream>>>(tmaa_r, tmaa_w, tmaa_k, tmaa_v, tmaa_a, tmaa_g, paux);
    wcvt_kernel<<<dim3(5760), 256, 0, stream>>>(w_recept, w_key, w_value, w_output, maa_w1, wb);
    xtr_kernel<<<dim3(32, 12, 2), 256, 0, stream>>>(x, xtb);

    // tm = tanh(maa_w1 @ x)  via bf16 MFMA
    maaw1_mfma_kernel<<<dim3(16, 3, 2), 256, 0, stream>>>(wb + 4L * 294912, xtb, tm);

    // X6[n] = x * (paux[n] + maa_w2[n]^T @ tm_n); bf16 side-write r/k/v;
    // fp32 store skipped for slots 0,3 (never read as fp32)
    gemm_kernel<1,0,0,2><<<dim3(32, 12, 12), 256, 0, stream>>>(
        maa_w2, tm, X6, paux, x,
        64, 768, TT, TT, 6,
        0, 64L * 768, 384L * TT, 64L * TT, CT, FF, 768, CT, X6b);

    // transpose bf16 conv inputs (C,T) -> (T,C)
    btr_kernel<<<dim3(32, 12, 6), 256, 0, stream>>>(X6b, X6t);

    // merged lora hiddens (decay/aaa/kkk/gate _w1, tanh)
    lorah_kernel<<<dim3(32, 3, 8), 256, 0, stream>>>(
        decay_w1, aaa_w1, kkk_w1, gate_w1, xw, xa, xk, xg, dh, ah, kh, gh);

    // merged 3 input convs via bf16 MFMA -> rB/kB/vB (fp32 (B,T,C))
    convs3_mfma_kernel<<<dim3(16, 3, 12), 256, 0, stream>>>(wb, X6t, X6);

    // lora outs -> (B,T,C)
    gemm_kernel<0,0,1,3><<<dim3(32, 12, 2), 256, 0, stream>>>(
        decay_w2, dh, wwB, tdecay, nullptr, 64, 64, TT, CC, 1,
        0, 0, 64L * TT, 0, TC, 0, 0, 0, nullptr);
    gemm_kernel<0,0,1,4><<<dim3(32, 12, 2), 256, 0, stream>>>(
        aaa_w2, ah, b2B /* a for now */, taaaaa, nullptr, 64, 64, TT, CC, 1,
        0, 0, 64L * TT, 0, TC, 0, 0, 0, nullptr);
    gemm_kernel<0,0,1,0><<<dim3(32, 12, 2), 256, 0, stream>>>(
        kkk_w2, kh, aaB /* kvec for now */, nullptr, nullptr, 64, 64, TT, CC, 1,
        0, 0, 64L * TT, 0, TC, 0, 0, 0, nullptr);
    gemm_kernel<0,0,1,0><<<dim3(32, 12, 2), 256, 0, stream>>>(
        gate_w2, gh, gbuf, nullptr, nullptr, 192, 192, TT, CC, 1,
        0, 0, 192L * TT, 0, TC, 0, 0, 0, nullptr);

    // E1: build aa (over kvec slot) and b2 (over a slot)
    e1_kernel<<<dim3(BB * TT), 256, 0, stream>>>(kB, aaB, b2B);

    // WKV v11: v9 packaging + bf16 y-partial stores (no y reduction)
    wkv_kernel<<<dim3(BB * HH * 8), 64, 0, stream>>>(rB, wwB, kB, vB, aaB, b2B, yp8);

    // E2: sum partials + rmsnorm + faaaa bonus + gate -> bf16 z
    e2_kernel<<<dim3(BB * TT), 256, 0, stream>>>(yp8, rB, kB, vB, gbuf, tfaaaa, lnw, zb);

    // final grouped conv via bf16 MFMA: z (B,T,C) -> out (B,C,T)
    convout_mfma_kernel<<<dim3(16, 3, 4), 256, 0, stream>>>(wb + 3L * 294912, zb, out);
}